// Round 9
// baseline (271.252 us; speedup 1.0000x reference)
//
#include <hip/hip_runtime.h>

// Problem constants (fixed by the reference)
#define N_NODES 16384
#define N_EDGES 262144
#define E_TOT   (N_EDGES + N_NODES)   // edges + self loops = 278528
#define NEG_SLOPE 0.2f

typedef __attribute__((ext_vector_type(8))) short short8;
typedef __attribute__((ext_vector_type(4))) float floatx4;
typedef __attribute__((ext_vector_type(4))) int intx4;

__device__ __forceinline__ float bf2f(ushort u) {
    return __uint_as_float(((unsigned)u) << 16);
}
__device__ __forceinline__ ushort f2bf(float f) {
    unsigned u = __float_as_uint(f);
    u += 0x7fffu + ((u >> 16) & 1u);   // round-to-nearest-even
    return (ushort)(u >> 16);
}
__device__ __forceinline__ float leaky(float x) {
    return x > 0.f ? x : NEG_SLOPE * x;
}

// async global->LDS, 16B per lane. LDS dest = wave-uniform base + lane*16
// (layout verified in R6; R6's failure was the divergent-shfl bug, fixed R8).
__device__ __forceinline__ void load_lds16(const void* g, void* l) {
    __builtin_amdgcn_global_load_lds(
        (const __attribute__((address_space(1))) unsigned int*)g,
        (__attribute__((address_space(3))) unsigned int*)l, 16, 0, 0);
}

// ---------------------------------------------------------------------------
// Fused prep: x f32->bf16 cast, 3 weight transposes (+bf16), counts zeroing.
// ---------------------------------------------------------------------------
#define PREP_CAST   524288
#define PREP_T0     (PREP_CAST)
#define PREP_T1     (PREP_T0 + 65536)
#define PREP_T2     (PREP_T1 + 131072)
#define PREP_Z      (PREP_T2 + 262144)
#define PREP_TOT    (PREP_Z + 4096)

__global__ __launch_bounds__(256) void k_prep(const float* __restrict__ x,
                                              ushort* __restrict__ xb,
                                              const float* __restrict__ Wfc,
                                              ushort* __restrict__ WfcT,
                                              const float* __restrict__ W1,
                                              ushort* __restrict__ W1T,
                                              const float* __restrict__ W2,
                                              ushort* __restrict__ W2T,
                                              int* __restrict__ counts) {
    int idx = blockIdx.x * 256 + threadIdx.x;
    if (idx < PREP_CAST) {
        floatx4 v0 = *(const floatx4*)(x + (size_t)idx * 8);
        floatx4 v1 = *(const floatx4*)(x + (size_t)idx * 8 + 4);
        short8 r;
        r[0] = (short)f2bf(v0[0]); r[1] = (short)f2bf(v0[1]);
        r[2] = (short)f2bf(v0[2]); r[3] = (short)f2bf(v0[3]);
        r[4] = (short)f2bf(v1[0]); r[5] = (short)f2bf(v1[1]);
        r[6] = (short)f2bf(v1[2]); r[7] = (short)f2bf(v1[3]);
        *(short8*)(xb + (size_t)idx * 8) = r;
    } else if (idx < PREP_T1) {
        int t = idx - PREP_T0;                 // K=256, N=256
        int k = t >> 8, n = t & 255;
        WfcT[n * 256 + k] = f2bf(Wfc[t]);
    } else if (idx < PREP_T2) {
        int t = idx - PREP_T1;                 // K=256, N=512
        int k = t >> 9, n = t & 511;
        W1T[n * 256 + k] = f2bf(W1[t]);
    } else if (idx < PREP_Z) {
        int t = idx - PREP_T2;                 // K=512, N=512
        int k = t >> 9, n = t & 511;
        W2T[n * 512 + k] = f2bf(W2[t]);
    } else if (idx < PREP_TOT) {
        int t = idx - PREP_Z;
        *(intx4*)(counts + t * 4) = (intx4){0, 0, 0, 0};
    }
}

// ---------------------------------------------------------------------------
// CSR build: histogram of dst, shfl-based scan, scatter src indices
// ---------------------------------------------------------------------------
__global__ __launch_bounds__(256) void k_hist(const int* __restrict__ adj,
                                              int* __restrict__ counts) {
    int e = blockIdx.x * 256 + threadIdx.x;
    if (e < E_TOT) {
        int d = (e < N_EDGES) ? adj[N_EDGES + e] : (e - N_EDGES);
        atomicAdd(&counts[d], 1);
    }
}

__global__ __launch_bounds__(1024) void k_scan(const int* __restrict__ counts,
                                               int* __restrict__ offs,
                                               int* __restrict__ cursor) {
    __shared__ int wsum[16];
    int t = threadIdx.x, lane = t & 63, w = t >> 6;
    int local[16];
    int tot = 0;
#pragma unroll
    for (int i = 0; i < 16; i++) {
        local[i] = tot;
        tot += counts[t * 16 + i];
    }
    int incl = tot;   // wave-inclusive scan over thread totals
#pragma unroll
    for (int d = 1; d < 64; d <<= 1) {
        int v = __shfl_up(incl, d, 64);
        if (lane >= d) incl += v;
    }
    if (lane == 63) wsum[w] = incl;
    __syncthreads();
    if (w == 0) {
        int v = (lane < 16) ? wsum[lane] : 0;
#pragma unroll
        for (int d = 1; d < 16; d <<= 1) {
            int u = __shfl_up(v, d, 64);
            if (lane >= d) v += u;
        }
        if (lane < 16) wsum[lane] = v;
    }
    __syncthreads();
    int base = ((w == 0) ? 0 : wsum[w - 1]) + incl - tot;
#pragma unroll
    for (int i = 0; i < 16; i++) {
        int o = base + local[i];
        offs[t * 16 + i] = o;
        cursor[t * 16 + i] = o;
    }
    if (t == 1023) offs[N_NODES] = wsum[15];
}

__global__ __launch_bounds__(256) void k_scatter(const int* __restrict__ adj,
                                                 int* __restrict__ cursor,
                                                 int* __restrict__ esrc) {
    int e = blockIdx.x * 256 + threadIdx.x;
    if (e < E_TOT) {
        int s, d;
        if (e < N_EDGES) { s = adj[e]; d = adj[N_EDGES + e]; }
        else             { s = e - N_EDGES; d = s; }
        int pos = atomicAdd(&cursor[d], 1);
        esrc[pos] = s;
    }
}

// ---------------------------------------------------------------------------
// 128x128-tile GEMM, async staging (m97 structure): BK=64, 4 waves (2x2 of
// 64x64), 4x4 MFMA tiles/wave. global_load_lds width=16, unpadded LDS
// [row][64] (dest = wave-uniform base + lane*16; lane i -> row i>>3,
// col (i&7)*8 — matches the global address map).
// mfma_f32_16x16x32_bf16 layouts (HW-verified):
//   A frag: A[m=lane&15][k=(lane>>4)*8 + j]
//   B frag: B[k=(lane>>4)*8 + j][n=lane&15]  (from BT rows)
//   C/D:    col=lane&15, row=(lane>>4)*4 + reg
// ---------------------------------------------------------------------------
#define GM 128
#define GN 128
#define GK 64

__global__ __launch_bounds__(256) void gemm128(const ushort* __restrict__ A,
                                               const ushort* __restrict__ BT,
                                               const float* __restrict__ bias,
                                               ushort* __restrict__ C,
                                               int M, int Nc, int K, int relu) {
    __shared__ ushort As[GM * GK];   // 16 KB
    __shared__ ushort Bs[GN * GK];   // 16 KB
    int tid = threadIdx.x, wave = tid >> 6, lane = tid & 63;
    int quad = lane >> 4, l16 = lane & 15;
    int bm = blockIdx.x * GM, bn = blockIdx.y * GN;
    int wm = (wave & 1) * 64, wn = (wave >> 1) * 64;

    floatx4 acc[4][4];
#pragma unroll
    for (int mi = 0; mi < 4; mi++)
#pragma unroll
        for (int ni = 0; ni < 4; ni++)
            acc[mi][ni] = (floatx4){0.f, 0.f, 0.f, 0.f};

    int lrow = lane >> 3;            // 0..7
    int lcol = (lane & 7) * 8;       // 0..56
    const ushort* pA = A + (size_t)(bm + wave * 32 + lrow) * K + lcol;
    const ushort* pB = BT + (size_t)(bn + wave * 32 + lrow) * K + lcol;
    ushort* lA = &As[(wave * 32) * GK];
    ushort* lB = &Bs[(wave * 32) * GK];

    for (int kb = 0; kb < K; kb += GK) {
#pragma unroll
        for (int t = 0; t < 4; t++) {
            load_lds16(pA + (size_t)(t * 8) * K + kb, lA + t * 8 * GK);
            load_lds16(pB + (size_t)(t * 8) * K + kb, lB + t * 8 * GK);
        }
        __syncthreads();   // vmcnt drained before barrier -> LDS data visible

#pragma unroll
        for (int kk = 0; kk < GK; kk += 32) {
            short8 af[4], bf[4];
#pragma unroll
            for (int mi = 0; mi < 4; mi++)
                af[mi] = *(const short8*)&As[(wm + mi * 16 + l16) * GK + kk + quad * 8];
#pragma unroll
            for (int ni = 0; ni < 4; ni++)
                bf[ni] = *(const short8*)&Bs[(wn + ni * 16 + l16) * GK + kk + quad * 8];
#pragma unroll
            for (int mi = 0; mi < 4; mi++)
#pragma unroll
                for (int ni = 0; ni < 4; ni++)
                    acc[mi][ni] = __builtin_amdgcn_mfma_f32_16x16x32_bf16(
                        af[mi], bf[ni], acc[mi][ni], 0, 0, 0);
        }
        __syncthreads();
    }

#pragma unroll
    for (int mi = 0; mi < 4; mi++) {
        int row = bm + wm + mi * 16 + quad * 4;
#pragma unroll
        for (int ni = 0; ni < 4; ni++) {
            int col = bn + wn + ni * 16 + l16;
            float bv = bias ? bias[col] : 0.f;
#pragma unroll
            for (int i = 0; i < 4; i++) {
                float v = acc[mi][ni][i] + bv;
                if (relu) v = fmaxf(v, 0.f);
                C[(size_t)(row + i) * Nc + col] = f2bf(v);
            }
        }
    }
}

// ---------------------------------------------------------------------------
// Attention logits: h bf16, a-vectors fp32. One wave per node.
// ---------------------------------------------------------------------------
__global__ __launch_bounds__(256) void k_dots(const ushort* __restrict__ h,
                                              const float* __restrict__ asrc,
                                              const float* __restrict__ adst,
                                              float* __restrict__ als,
                                              float* __restrict__ ald,
                                              int heads) {
    int wave = threadIdx.x >> 6, lane = threadIdx.x & 63;
    int n = blockIdx.x * 4 + wave;
    const ushort* hr = h + (size_t)n * 512;
    int c = lane * 8;
    short8 hv = *(const short8*)(hr + c);
    floatx4 s0 = *(const floatx4*)(asrc + c);
    floatx4 s1 = *(const floatx4*)(asrc + c + 4);
    floatx4 d0 = *(const floatx4*)(adst + c);
    floatx4 d1 = *(const floatx4*)(adst + c + 4);
    float ps = 0.f, pd = 0.f;
#pragma unroll
    for (int j = 0; j < 4; j++) {
        float hf0 = bf2f((ushort)hv[j]);
        float hf1 = bf2f((ushort)hv[j + 4]);
        ps += hf0 * s0[j] + hf1 * s1[j];
        pd += hf0 * d0[j] + hf1 * d1[j];
    }
    int w = (heads == 2) ? 32 : 64;
    for (int m = 1; m < w; m <<= 1) {
        ps += __shfl_xor(ps, m, 64);
        pd += __shfl_xor(pd, m, 64);
    }
    if (heads == 2) {
        if (lane == 0)  { als[n * 2]     = ps; ald[n * 2]     = pd; }
        if (lane == 32) { als[n * 2 + 1] = ps; ald[n * 2 + 1] = pd; }
    } else {
        if (lane == 0)  { als[n] = ps; ald[n] = pd; }
    }
}

// ---------------------------------------------------------------------------
// Segment softmax + aggregation, TWO waves per node (R9): waves split edges
// by parity (wave sub handles edges 2j+sub), halving the serial gather chain
// and doubling in-flight loads per node. Partials combined via LDS by sub=0.
// All __shfl broadcasts unconditional (R8 lesson: never shfl under
// myhead-divergent control flow).
// Block 256 = 4 waves = 2 nodes. Grid N_NODES/2.
// ---------------------------------------------------------------------------
__global__ __launch_bounds__(256) void k_agg(const ushort* __restrict__ h,
                                             const float* __restrict__ als,
                                             const float* __restrict__ ald,
                                             const int* __restrict__ offs,
                                             const int* __restrict__ esrc,
                                             const float* __restrict__ bias,
                                             ushort* __restrict__ outb,
                                             float* __restrict__ outf,
                                             int heads) {
    __shared__ float sPart[2][512];
    int wave = threadIdx.x >> 6, lane = threadIdx.x & 63;
    int nib = wave >> 1;          // node-in-block 0/1
    int sub = wave & 1;           // edge-parity subset
    int n = blockIdx.x * 2 + nib;
    int base = offs[n];
    int deg  = offs[n + 1] - base;

    int myhead = (heads == 2) ? (lane >> 5) : 0;
    int c = (heads == 2) ? (myhead * 256 + (lane & 31) * 8) : lane * 8;

    float aldh0 = ald[n * heads];
    float aldh1 = (heads == 2) ? ald[n * heads + 1] : 0.f;

    // pass 1: per-head max (redundant in both waves of the pair; deg ~17)
    float m0 = -1e30f, m1 = -1e30f;
    for (int cb = 0; cb < deg; cb += 64) {
        int i = cb + lane;
        if (i < deg) {
            int s = esrc[base + i];
            m0 = fmaxf(m0, leaky(als[s * heads] + aldh0));
            if (heads == 2) m1 = fmaxf(m1, leaky(als[s * 2 + 1] + aldh1));
        }
    }
#pragma unroll
    for (int msk = 1; msk < 64; msk <<= 1) {
        m0 = fmaxf(m0, __shfl_xor(m0, msk, 64));
        m1 = fmaxf(m1, __shfl_xor(m1, msk, 64));
    }

    // pass 2: per-head denom
    float s0 = 0.f, s1 = 0.f;
    for (int cb = 0; cb < deg; cb += 64) {
        int i = cb + lane;
        if (i < deg) {
            int s = esrc[base + i];
            s0 += __expf(leaky(als[s * heads] + aldh0) - m0);
            if (heads == 2) s1 += __expf(leaky(als[s * 2 + 1] + aldh1) - m1);
        }
    }
#pragma unroll
    for (int msk = 1; msk < 64; msk <<= 1) {
        s0 += __shfl_xor(s0, msk, 64);
        s1 += __shfl_xor(s1, msk, 64);
    }
    float inv0 = 1.f / (s0 + 1e-16f);
    float inv1 = 1.f / (s1 + 1e-16f);

    // pass 3: this wave gathers edges cb + 2*j + sub (parity split)
    float acc[8];
#pragma unroll
    for (int q = 0; q < 8; q++) acc[q] = 0.f;
    const ushort* hc = h + c;

    for (int cb = 0; cb < deg; cb += 128) {
        int ei = cb + lane * 2 + sub;     // lane-held edge of this wave
        int sv = 0;
        float p0 = 0.f, p1 = 0.f;
        if (ei < deg) {
            sv = esrc[base + ei];
            p0 = __expf(leaky(als[sv * heads] + aldh0) - m0) * inv0;
            if (heads == 2) p1 = __expf(leaky(als[sv * 2 + 1] + aldh1) - m1) * inv1;
        }
        int cnt = min(128, deg - cb);
        int nw = (cnt > sub) ? ((cnt - sub + 1) >> 1) : 0;   // edges this wave
        int j = 0;
        for (; j + 4 <= nw; j += 4) {
            int sj0 = __shfl(sv, j, 64);
            int sj1 = __shfl(sv, j + 1, 64);
            int sj2 = __shfl(sv, j + 2, 64);
            int sj3 = __shfl(sv, j + 3, 64);
            float a00 = __shfl(p0, j, 64),     a01 = __shfl(p1, j, 64);
            float a10 = __shfl(p0, j + 1, 64), a11 = __shfl(p1, j + 1, 64);
            float a20 = __shfl(p0, j + 2, 64), a21 = __shfl(p1, j + 2, 64);
            float a30 = __shfl(p0, j + 3, 64), a31 = __shfl(p1, j + 3, 64);
            float al0 = myhead ? a01 : a00;
            float al1 = myhead ? a11 : a10;
            float al2 = myhead ? a21 : a20;
            float al3 = myhead ? a31 : a30;
            short8 h0v = *(const short8*)(hc + (size_t)sj0 * 512);
            short8 h1v = *(const short8*)(hc + (size_t)sj1 * 512);
            short8 h2v = *(const short8*)(hc + (size_t)sj2 * 512);
            short8 h3v = *(const short8*)(hc + (size_t)sj3 * 512);
#pragma unroll
            for (int q = 0; q < 8; q++) {
                acc[q] += al0 * bf2f((ushort)h0v[q]);
                acc[q] += al1 * bf2f((ushort)h1v[q]);
                acc[q] += al2 * bf2f((ushort)h2v[q]);
                acc[q] += al3 * bf2f((ushort)h3v[q]);
            }
        }
        for (; j < nw; j++) {
            int s = __shfl(sv, j, 64);
            float a0 = __shfl(p0, j, 64), a1 = __shfl(p1, j, 64);
            float al = myhead ? a1 : a0;
            short8 hv = *(const short8*)(hc + (size_t)s * 512);
#pragma unroll
            for (int q = 0; q < 8; q++) acc[q] += al * bf2f((ushort)hv[q]);
        }
    }

    // combine partials: sub=1 stores, sub=0 adds + epilogue
    if (sub == 1) {
#pragma unroll
        for (int q = 0; q < 8; q++) sPart[nib][c + q] = acc[q];
    }
    __syncthreads();
    if (sub == 0) {
        float v[8];
#pragma unroll
        for (int q = 0; q < 8; q++)
            v[q] = fmaxf(acc[q] + sPart[nib][c + q] + bias[c + q], 0.f);
        if (outf) {
            float* op = outf + (size_t)n * 512 + c;
            *(floatx4*)op       = (floatx4){v[0], v[1], v[2], v[3]};
            *(floatx4*)(op + 4) = (floatx4){v[4], v[5], v[6], v[7]};
        } else {
            short8 r;
#pragma unroll
            for (int q = 0; q < 8; q++) r[q] = (short)f2bf(v[q]);
            *(short8*)(outb + (size_t)n * 512 + c) = r;
        }
    }
}

// ---------------------------------------------------------------------------
// R9: gemm128 async global_load_lds staging (exonerated by R8's root cause);
// k_agg 2 waves/node parity split. Workspace ~52 MiB.
// ---------------------------------------------------------------------------
extern "C" void kernel_launch(void* const* d_in, const int* in_sizes, int n_in,
                              void* d_out, int out_size, void* d_ws, size_t ws_size,
                              hipStream_t stream) {
    const float* x   = (const float*)d_in[0];
    const int*   adj = (const int*)d_in[1];
    const float* Wfc = (const float*)d_in[2];
    const float* bfc = (const float*)d_in[3];
    const float* W1  = (const float*)d_in[4];
    const float* a1s = (const float*)d_in[5];
    const float* a1d = (const float*)d_in[6];
    const float* b1  = (const float*)d_in[7];
    const float* W2  = (const float*)d_in[8];
    const float* a2s = (const float*)d_in[9];
    const float* a2d = (const float*)d_in[10];
    const float* b2  = (const float*)d_in[11];
    float* out = (float*)d_out;

    char* ws = (char*)d_ws;
    size_t off = 0;
    auto alloc = [&](size_t bytes) -> void* {
        void* p = ws + off;
        off += (bytes + 255) & ~(size_t)255;
        return p;
    };
    ushort* xb   = (ushort*)alloc((size_t)N_NODES * 256 * 2);
    ushort* h0b  = (ushort*)alloc((size_t)N_NODES * 256 * 2);
    ushort* h1b  = (ushort*)alloc((size_t)N_NODES * 512 * 2);
    ushort* g1b  = (ushort*)alloc((size_t)N_NODES * 512 * 2);
    int* counts  = (int*)alloc(N_NODES * 4);
    int* offs    = (int*)alloc((N_NODES + 1) * 4);
    int* cursor  = (int*)alloc(N_NODES * 4);
    int* esrc    = (int*)alloc(E_TOT * 4);
    ushort* WfcT = (ushort*)alloc(256 * 256 * 2);
    ushort* W1T  = (ushort*)alloc(512 * 256 * 2);
    ushort* W2T  = (ushort*)alloc(512 * 512 * 2);
    float* als1  = (float*)alloc(N_NODES * 2 * 4);
    float* ald1  = (float*)alloc(N_NODES * 2 * 4);
    float* als2  = (float*)alloc(N_NODES * 4);
    float* ald2  = (float*)alloc(N_NODES * 4);

    // fused prep: cast x, transpose 3 weights, zero counts
    k_prep<<<PREP_TOT / 256, 256, 0, stream>>>(x, xb, Wfc, WfcT, W1, W1T, W2, W2T,
                                               counts);

    // CSR build
    k_hist<<<(E_TOT + 255) / 256, 256, 0, stream>>>(adj, counts);
    k_scan<<<1, 1024, 0, stream>>>(counts, offs, cursor);
    k_scatter<<<(E_TOT + 255) / 256, 256, 0, stream>>>(adj, cursor, esrc);

    // h0 = relu(x @ Wfc + bfc)            [N,256] bf16
    gemm128<<<dim3(N_NODES / GM, 256 / GN), 256, 0, stream>>>(xb, WfcT, bfc, h0b,
                                                              N_NODES, 256, 256, 1);
    // h1 = h0 @ W1                        [N,512] bf16
    gemm128<<<dim3(N_NODES / GM, 512 / GN), 256, 0, stream>>>(h0b, W1T, nullptr, h1b,
                                                              N_NODES, 512, 256, 0);
    // gat1 attention + aggregation -> relu -> g1b (bf16)
    k_dots<<<N_NODES / 4, 256, 0, stream>>>(h1b, a1s, a1d, als1, ald1, 2);
    k_agg<<<N_NODES / 2, 256, 0, stream>>>(h1b, als1, ald1, offs, esrc, b1,
                                           g1b, nullptr, 2);

    // h2 = g1 @ W2                        [N,512] bf16 (h1b reused; h1 dead)
    gemm128<<<dim3(N_NODES / GM, 512 / GN), 256, 0, stream>>>(g1b, W2T, nullptr, h1b,
                                                              N_NODES, 512, 512, 0);
    // gat2 attention + aggregation -> relu -> out (fp32)
    k_dots<<<N_NODES / 4, 256, 0, stream>>>(h1b, a2s, a2d, als2, ald2, 1);
    k_agg<<<N_NODES / 2, 256, 0, stream>>>(h1b, als2, ald2, offs, esrc, b2,
                                           nullptr, out, 1);
}